// Round 10
// baseline (303.697 us; speedup 1.0000x reference)
//
#include <hip/hip_runtime.h>

typedef unsigned short u16;
typedef __attribute__((ext_vector_type(8))) short bf16x8;
typedef __attribute__((ext_vector_type(4))) float f32x4;

#define MFMA16(A,B,C) __builtin_amdgcn_mfma_f32_16x16x32_bf16(A,B,C,0,0,0)

#define B_ 4
#define C_ 256
#define N_ 2304
#define HEADS_ 8
#define DH_ 64
#define INNER_ 512
#define SCALE_LOG2E 14.426950408889634f   // 10 * log2(e); also the fixed max bias

__device__ __forceinline__ u16 f2bf(float f) {
    union { float f; unsigned int u; } v; v.f = f;
    unsigned int r = v.u + 0x7fffu + ((v.u >> 16) & 1u);
    return (u16)(r >> 16);
}
// pack two floats to bf16x2 (round-half-up) in 3 VALU ops: add, add, v_perm
__device__ __forceinline__ unsigned int pk2(float a, float b) {
    union { float f; unsigned int u; } va, vb; va.f = a; vb.f = b;
    return __builtin_amdgcn_perm(vb.u + 0x8000u, va.u + 0x8000u, 0x07060302u);
}

// ---------------- Kernel P: fused prep (transpose x + convert weights) ----------------
// blocks [0,576): transpose x [B][C][N] f32 -> xT [B][N][C] bf16
// blocks [576,960): cvt w_qkv; blocks [960,1088): cvt w_out
__global__ __launch_bounds__(256) void k_prep(const float* __restrict__ x,
                                              u16* __restrict__ xT,
                                              const float* __restrict__ w_qkv,
                                              u16* __restrict__ wqb,
                                              const float* __restrict__ w_out,
                                              u16* __restrict__ wob) {
    __shared__ float tile[64][65];
    int idx = blockIdx.x;
    int t = threadIdx.x;
    if (idx < 576) {
        int b = idx / 144, rem = idx % 144;
        int n0 = (rem >> 2) * 64, c0 = (rem & 3) * 64;
        const float* xb = x + (size_t)b * C_ * N_;
        u16* xTb = xT + (size_t)b * N_ * C_;
        int r = t >> 4;
        int q4 = (t & 15) * 4;
#pragma unroll
        for (int pass = 0; pass < 4; ++pass) {
            int c = r + pass * 16;
            float4 v = *(const float4*)(xb + (size_t)(c0 + c) * N_ + n0 + q4);
            tile[c][q4+0] = v.x; tile[c][q4+1] = v.y; tile[c][q4+2] = v.z; tile[c][q4+3] = v.w;
        }
        __syncthreads();
#pragma unroll
        for (int pass = 0; pass < 4; ++pass) {
            int n = r + pass * 16;
            ushort4 o;
            o.x = f2bf(tile[q4+0][n]); o.y = f2bf(tile[q4+1][n]);
            o.z = f2bf(tile[q4+2][n]); o.w = f2bf(tile[q4+3][n]);
            *(ushort4*)(xTb + (size_t)(n0 + n) * C_ + c0 + q4) = o;
        }
    } else if (idx < 960) {
        int i = (idx - 576) * 256 + t;          // < 98304
        float4 v = ((const float4*)w_qkv)[i];
        ushort4 o;
        o.x = f2bf(v.x); o.y = f2bf(v.y); o.z = f2bf(v.z); o.w = f2bf(v.w);
        ((ushort4*)wqb)[i] = o;
    } else {
        int i = (idx - 960) * 256 + t;          // < 32768
        float4 v = ((const float4*)w_out)[i];
        ushort4 o;
        o.x = f2bf(v.x); o.y = f2bf(v.y); o.z = f2bf(v.z); o.w = f2bf(v.w);
        ((ushort4*)wob)[i] = o;
    }
}

// ---------------- Kernel 1: QKV GEMM (LDS-staged) + l2norm(q,k) ----------------
__global__ __launch_bounds__(256) void k_qkv(const u16* __restrict__ w_qkv,
                                             const u16* __restrict__ xT,
                                             u16* __restrict__ Qn,
                                             u16* __restrict__ Kn,
                                             u16* __restrict__ Vt) {
    __shared__ __align__(16) u16 Wt[64][264];
    __shared__ __align__(16) u16 Xt[64][264];
    int mt = blockIdx.x, nt = blockIdx.y, b = blockIdx.z;
    int tid = threadIdx.x;
    int wv = tid >> 6, lane = tid & 63;
    int col = lane & 15, quad = lane >> 4;
    int o0 = mt * 64;
    const u16* wtile = w_qkv + (size_t)o0 * C_;
    const u16* xtile = xT + ((size_t)b * N_ + nt*64) * C_;
#pragma unroll
    for (int p = 0; p < 8; ++p) {
        int c = p * 256 + tid;
        int row = c >> 5, seg = c & 31;
        *(uint4*)(&Wt[row][seg*8]) = *(const uint4*)(wtile + (size_t)row * C_ + seg*8);
        *(uint4*)(&Xt[row][seg*8]) = *(const uint4*)(xtile + (size_t)row * C_ + seg*8);
    }
    __syncthreads();
    f32x4 z = {0.f, 0.f, 0.f, 0.f};
    f32x4 acc[4]; acc[0]=z; acc[1]=z; acc[2]=z; acc[3]=z;
#pragma unroll
    for (int ks = 0; ks < 8; ++ks) {
        bf16x8 bfrag = *(const bf16x8*)(&Xt[wv*16 + col][ks*32 + quad*8]);
#pragma unroll
        for (int mb = 0; mb < 4; ++mb) {
            bf16x8 afrag = *(const bf16x8*)(&Wt[mb*16 + col][ks*32 + quad*8]);
            acc[mb] = MFMA16(afrag, bfrag, acc[mb]);
        }
    }
    int n = nt * 64 + wv * 16 + col;
    int which = mt >> 3, h = mt & 7;
    if (which < 2) {
        float s = 0.f;
#pragma unroll
        for (int mb = 0; mb < 4; ++mb)
#pragma unroll
            for (int r = 0; r < 4; ++r) s += acc[mb][r] * acc[mb][r];
        s += __shfl_xor(s, 16);
        s += __shfl_xor(s, 32);
        float inv = 1.f / fmaxf(sqrtf(s), 1e-12f);
        u16* dst = (which == 0 ? Qn : Kn) + (((size_t)b * HEADS_ + h) * N_ + n) * DH_;
#pragma unroll
        for (int mb = 0; mb < 4; ++mb) {
            ushort4 o;
            o.x = f2bf(acc[mb][0] * inv); o.y = f2bf(acc[mb][1] * inv);
            o.z = f2bf(acc[mb][2] * inv); o.w = f2bf(acc[mb][3] * inv);
            *(ushort4*)(dst + mb*16 + quad*4) = o;
        }
    } else {
        u16* dst = Vt + ((size_t)b * HEADS_ + h) * (size_t)DH_ * N_;
#pragma unroll
        for (int mb = 0; mb < 4; ++mb)
#pragma unroll
            for (int r = 0; r < 4; ++r)
                dst[(size_t)(mb*16 + quad*4 + r) * N_ + n] = f2bf(acc[mb][r]);
    }
}

// ---------------- Kernel 2: flash attention (S^T/O^T, fixed-max, reg-prefetch) ----
// |q.k| <= 1 (l2-normalized) -> constant max = 10. Tile kt+1 is prefetched into
// VGPRs during compute of tile kt; regs commit to LDS at the top of the next iter.
__global__ __launch_bounds__(256) void k_attn(const u16* __restrict__ Qn,
                                              const u16* __restrict__ Kn,
                                              const u16* __restrict__ Vt,
                                              u16* __restrict__ AO) {
    __shared__ __align__(16) u16 Kt[64][72];        // k-rows x d (pad 8)
    __shared__ __align__(16) u16 Vtl[64][72];       // d-rows x k (pad 8)
    __shared__ __align__(16) u16 plds[4][16][72];   // per-wave P^T [q][k]
    int head_lin = blockIdx.x & 31;                 // head -> XCD pinning
    int qt = blockIdx.x >> 5;                       // 0..35
    int b = head_lin >> 3, h = head_lin & 7;
    int tid = threadIdx.x;
    int wv = tid >> 6, lane = tid & 63;
    int col = lane & 15, quad = lane >> 4;
    size_t head = (size_t)b * HEADS_ + h;
    const u16* Qh = Qn + head * (size_t)N_ * DH_;
    const u16* Kh = Kn + head * (size_t)N_ * DH_;
    const u16* Vh = Vt + head * (size_t)DH_ * N_;
    int q0 = qt * 64 + wv * 16;
    bf16x8 qf0 = *(const bf16x8*)(Qh + (size_t)(q0 + col) * DH_ + quad*8);
    bf16x8 qf1 = *(const bf16x8*)(Qh + (size_t)(q0 + col) * DH_ + 32 + quad*8);
    f32x4 z = {0.f, 0.f, 0.f, 0.f};
    f32x4 O[4]; O[0]=z; O[1]=z; O[2]=z; O[3]=z;
    float l_i = 0.f;
    int vrow0 = tid >> 3, vseg = tid & 7;           // V staging coords
    const u16* ksrc0 = Kh + (size_t)tid * 8;        // lane-fixed K source
    const u16* vsrc0 = Vh + (size_t)vrow0 * N_ + vseg * 8;

    uint4 kreg[2], vreg[2];
#pragma unroll
    for (int p = 0; p < 2; ++p) {                   // prefetch tile 0
        kreg[p] = *(const uint4*)(ksrc0 + p*2048);
        vreg[p] = *(const uint4*)(vsrc0 + (size_t)p * 32 * N_);
    }

    for (int kt = 0; kt < N_/64; ++kt) {            // 36 iterations
        // commit prefetched tile to LDS
#pragma unroll
        for (int p = 0; p < 2; ++p) {
            int c = p * 256 + tid;
            *(uint4*)(&Kt[c >> 3][(c & 7) * 8]) = kreg[p];
            *(uint4*)(&Vtl[p*32 + vrow0][vseg*8]) = vreg[p];
        }
        __syncthreads();   // tile visible
        // prefetch tile kt+1 (latency hidden behind compute below)
        if (kt + 1 < N_/64) {
#pragma unroll
            for (int p = 0; p < 2; ++p) {
                kreg[p] = *(const uint4*)(ksrc0 + p*2048 + (size_t)(kt+1) * 4096);
                vreg[p] = *(const uint4*)(vsrc0 + (size_t)p * 32 * N_ + (kt+1) * 64);
            }
        }
        // S^T + fixed-max softmax + pack, per 16-k block
        float rs = 0.f;
#pragma unroll
        for (int nb = 0; nb < 4; ++nb) {
            f32x4 a = z;
            a = MFMA16(*(const bf16x8*)(&Kt[nb*16 + col][quad*8]), qf0, a);
            a = MFMA16(*(const bf16x8*)(&Kt[nb*16 + col][32 + quad*8]), qf1, a);
            float p0 = exp2f(fmaf(a[0], SCALE_LOG2E, -SCALE_LOG2E));
            float p1 = exp2f(fmaf(a[1], SCALE_LOG2E, -SCALE_LOG2E));
            float p2 = exp2f(fmaf(a[2], SCALE_LOG2E, -SCALE_LOG2E));
            float p3 = exp2f(fmaf(a[3], SCALE_LOG2E, -SCALE_LOG2E));
            rs += (p0 + p1) + (p2 + p3);
            uint2 w;
            w.x = pk2(p0, p1);
            w.y = pk2(p2, p3);
            *(uint2*)(&plds[wv][col][nb*16 + quad*4]) = w;
        }
        l_i += rs;
        // wave-private plds: compiler fence; DS pipe is in-order per wave
        __asm__ volatile("" ::: "memory");
        // O^T += V^T P^T
#pragma unroll
        for (int ks = 0; ks < 2; ++ks) {
            bf16x8 pf = *(const bf16x8*)(&plds[wv][col][ks*32 + quad*8]);
#pragma unroll
            for (int nb = 0; nb < 4; ++nb) {
                bf16x8 vf = *(const bf16x8*)(&Vtl[nb*16 + col][ks*32 + quad*8]);
                O[nb] = MFMA16(vf, pf, O[nb]);
            }
        }
        __asm__ volatile("" ::: "memory");   // WAR vs next iter's plds writes
        __syncthreads();   // all tile reads done before next iter's commits
    }
    // combine l across quads (disjoint k-subsets, same q=col)
    l_i += __shfl_xor(l_i, 16);
    l_i += __shfl_xor(l_i, 32);
    float linv = 1.f / l_i;
    u16* dst = AO + ((size_t)b * N_ + q0 + col) * INNER_ + h * DH_;
#pragma unroll
    for (int nb = 0; nb < 4; ++nb) {
        uint2 w;
        w.x = pk2(O[nb][0] * linv, O[nb][1] * linv);
        w.y = pk2(O[nb][2] * linv, O[nb][3] * linv);
        *(uint2*)(dst + nb*16 + quad*4) = w;
    }
}

// ---------------- Kernel 3: output projection (LDS-staged) + bias ----------------
__global__ __launch_bounds__(256) void k_proj(const u16* __restrict__ w_out,
                                              const float* __restrict__ b_out,
                                              const u16* __restrict__ AO,
                                              float* __restrict__ out) {
    __shared__ __align__(16) u16 Wt[64][264];
    __shared__ __align__(16) u16 At[64][264];
    int mt = blockIdx.x, nt = blockIdx.y, b = blockIdx.z;
    int tid = threadIdx.x;
    int wv = tid >> 6, lane = tid & 63;
    int col = lane & 15, quad = lane >> 4;
    int o0b = mt * 64;
    const u16* wtile = w_out + (size_t)o0b * INNER_;
    const u16* atile = AO + ((size_t)b * N_ + nt*64) * INNER_;
    f32x4 z = {0.f, 0.f, 0.f, 0.f};
    f32x4 acc[4]; acc[0]=z; acc[1]=z; acc[2]=z; acc[3]=z;
#pragma unroll
    for (int half = 0; half < 2; ++half) {
        if (half) __syncthreads();
#pragma unroll
        for (int p = 0; p < 8; ++p) {
            int c = p * 256 + tid;
            int row = c >> 5, seg = c & 31;
            *(uint4*)(&Wt[row][seg*8]) =
                *(const uint4*)(wtile + (size_t)row * INNER_ + half*256 + seg*8);
            *(uint4*)(&At[row][seg*8]) =
                *(const uint4*)(atile + (size_t)row * INNER_ + half*256 + seg*8);
        }
        __syncthreads();
#pragma unroll
        for (int ks = 0; ks < 8; ++ks) {
            bf16x8 af = *(const bf16x8*)(&Wt[wv*16 + col][ks*32 + quad*8]);
#pragma unroll
            for (int nb = 0; nb < 4; ++nb) {
                bf16x8 bfv = *(const bf16x8*)(&At[nb*16 + col][ks*32 + quad*8]);
                acc[nb] = MFMA16(af, bfv, acc[nb]);
            }
        }
    }
    int o0 = o0b + wv * 16;
    float bias[4];
#pragma unroll
    for (int r = 0; r < 4; ++r) bias[r] = b_out[o0 + quad*4 + r];
    float* dst = out + ((size_t)b * C_ + o0) * N_ + nt*64;
#pragma unroll
    for (int nb = 0; nb < 4; ++nb)
#pragma unroll
        for (int r = 0; r < 4; ++r)
            dst[(size_t)(quad*4 + r) * N_ + nb*16 + col] = acc[nb][r] + bias[r];
}

// ---------------- launch ----------------
extern "C" void kernel_launch(void* const* d_in, const int* in_sizes, int n_in,
                              void* d_out, int out_size, void* d_ws, size_t ws_size,
                              hipStream_t stream) {
    const float* x     = (const float*)d_in[0];
    const float* w_qkv = (const float*)d_in[1];
    const float* w_out = (const float*)d_in[2];
    const float* b_out = (const float*)d_in[3];
    float* out = (float*)d_out;

    char* ws = (char*)d_ws;
    u16* xT  = (u16*)(ws);
    u16* Qn  = (u16*)(ws + 4718592);
    u16* Kn  = (u16*)(ws + 14155776);
    u16* Vt  = (u16*)(ws + 23592960);
    u16* AO  = (u16*)(ws + 33030144);
    u16* wqb = (u16*)(ws + 42467328);
    u16* wob = (u16*)(ws + 43253760);

    hipLaunchKernelGGL(k_prep, dim3(1088), dim3(256), 0, stream, x, xT, w_qkv, wqb, w_out, wob);
    hipLaunchKernelGGL(k_qkv,  dim3(24, N_/64, B_), dim3(256), 0, stream, wqb, xT, Qn, Kn, Vt);
    hipLaunchKernelGGL(k_attn, dim3((N_/64) * 32), dim3(256), 0, stream, Qn, Kn, Vt, AO);
    hipLaunchKernelGGL(k_proj, dim3(C_/64, N_/64, B_), dim3(256), 0, stream, wob, b_out, AO, out);
}

// Round 11
// 197.294 us; speedup vs baseline: 1.5393x; 1.5393x over previous
//
#include <hip/hip_runtime.h>

typedef unsigned short u16;
typedef __attribute__((ext_vector_type(8))) short bf16x8;
typedef __attribute__((ext_vector_type(4))) float f32x4;

#define MFMA16(A,B,C) __builtin_amdgcn_mfma_f32_16x16x32_bf16(A,B,C,0,0,0)

#define B_ 4
#define C_ 256
#define N_ 2304
#define HEADS_ 8
#define DH_ 64
#define INNER_ 512
#define SCALE_LOG2E 14.426950408889634f   // 10 * log2(e); also the fixed max bias

__device__ __forceinline__ u16 f2bf(float f) {
    union { float f; unsigned int u; } v; v.f = f;
    unsigned int r = v.u + 0x7fffu + ((v.u >> 16) & 1u);
    return (u16)(r >> 16);
}
// pack two floats to bf16x2 (round-half-up) in 3 VALU ops: add, add, v_perm
__device__ __forceinline__ unsigned int pk2(float a, float b) {
    union { float f; unsigned int u; } va, vb; va.f = a; vb.f = b;
    return __builtin_amdgcn_perm(vb.u + 0x8000u, va.u + 0x8000u, 0x07060302u);
}

// ---------------- Kernel P: fused prep (transpose x + convert weights) ----------------
__global__ __launch_bounds__(256) void k_prep(const float* __restrict__ x,
                                              u16* __restrict__ xT,
                                              const float* __restrict__ w_qkv,
                                              u16* __restrict__ wqb,
                                              const float* __restrict__ w_out,
                                              u16* __restrict__ wob) {
    __shared__ float tile[64][65];
    int idx = blockIdx.x;
    int t = threadIdx.x;
    if (idx < 576) {
        int b = idx / 144, rem = idx % 144;
        int n0 = (rem >> 2) * 64, c0 = (rem & 3) * 64;
        const float* xb = x + (size_t)b * C_ * N_;
        u16* xTb = xT + (size_t)b * N_ * C_;
        int r = t >> 4;
        int q4 = (t & 15) * 4;
#pragma unroll
        for (int pass = 0; pass < 4; ++pass) {
            int c = r + pass * 16;
            float4 v = *(const float4*)(xb + (size_t)(c0 + c) * N_ + n0 + q4);
            tile[c][q4+0] = v.x; tile[c][q4+1] = v.y; tile[c][q4+2] = v.z; tile[c][q4+3] = v.w;
        }
        __syncthreads();
#pragma unroll
        for (int pass = 0; pass < 4; ++pass) {
            int n = r + pass * 16;
            ushort4 o;
            o.x = f2bf(tile[q4+0][n]); o.y = f2bf(tile[q4+1][n]);
            o.z = f2bf(tile[q4+2][n]); o.w = f2bf(tile[q4+3][n]);
            *(ushort4*)(xTb + (size_t)(n0 + n) * C_ + c0 + q4) = o;
        }
    } else if (idx < 960) {
        int i = (idx - 576) * 256 + t;
        float4 v = ((const float4*)w_qkv)[i];
        ushort4 o;
        o.x = f2bf(v.x); o.y = f2bf(v.y); o.z = f2bf(v.z); o.w = f2bf(v.w);
        ((ushort4*)wqb)[i] = o;
    } else {
        int i = (idx - 960) * 256 + t;
        float4 v = ((const float4*)w_out)[i];
        ushort4 o;
        o.x = f2bf(v.x); o.y = f2bf(v.y); o.z = f2bf(v.z); o.w = f2bf(v.w);
        ((ushort4*)wob)[i] = o;
    }
}

// ---------------- Kernel 1: QKV GEMM (LDS-staged) + l2norm(q,k) ----------------
__global__ __launch_bounds__(256) void k_qkv(const u16* __restrict__ w_qkv,
                                             const u16* __restrict__ xT,
                                             u16* __restrict__ Qn,
                                             u16* __restrict__ Kn,
                                             u16* __restrict__ Vt) {
    __shared__ __align__(16) u16 Wt[64][264];
    __shared__ __align__(16) u16 Xt[64][264];
    int mt = blockIdx.x, nt = blockIdx.y, b = blockIdx.z;
    int tid = threadIdx.x;
    int wv = tid >> 6, lane = tid & 63;
    int col = lane & 15, quad = lane >> 4;
    int o0 = mt * 64;
    const u16* wtile = w_qkv + (size_t)o0 * C_;
    const u16* xtile = xT + ((size_t)b * N_ + nt*64) * C_;
#pragma unroll
    for (int p = 0; p < 8; ++p) {
        int c = p * 256 + tid;
        int row = c >> 5, seg = c & 31;
        *(uint4*)(&Wt[row][seg*8]) = *(const uint4*)(wtile + (size_t)row * C_ + seg*8);
        *(uint4*)(&Xt[row][seg*8]) = *(const uint4*)(xtile + (size_t)row * C_ + seg*8);
    }
    __syncthreads();
    f32x4 z = {0.f, 0.f, 0.f, 0.f};
    f32x4 acc[4]; acc[0]=z; acc[1]=z; acc[2]=z; acc[3]=z;
#pragma unroll
    for (int ks = 0; ks < 8; ++ks) {
        bf16x8 bfrag = *(const bf16x8*)(&Xt[wv*16 + col][ks*32 + quad*8]);
#pragma unroll
        for (int mb = 0; mb < 4; ++mb) {
            bf16x8 afrag = *(const bf16x8*)(&Wt[mb*16 + col][ks*32 + quad*8]);
            acc[mb] = MFMA16(afrag, bfrag, acc[mb]);
        }
    }
    int n = nt * 64 + wv * 16 + col;
    int which = mt >> 3, h = mt & 7;
    if (which < 2) {
        float s = 0.f;
#pragma unroll
        for (int mb = 0; mb < 4; ++mb)
#pragma unroll
            for (int r = 0; r < 4; ++r) s += acc[mb][r] * acc[mb][r];
        s += __shfl_xor(s, 16);
        s += __shfl_xor(s, 32);
        float inv = 1.f / fmaxf(sqrtf(s), 1e-12f);
        u16* dst = (which == 0 ? Qn : Kn) + (((size_t)b * HEADS_ + h) * N_ + n) * DH_;
#pragma unroll
        for (int mb = 0; mb < 4; ++mb) {
            ushort4 o;
            o.x = f2bf(acc[mb][0] * inv); o.y = f2bf(acc[mb][1] * inv);
            o.z = f2bf(acc[mb][2] * inv); o.w = f2bf(acc[mb][3] * inv);
            *(ushort4*)(dst + mb*16 + quad*4) = o;
        }
    } else {
        u16* dst = Vt + ((size_t)b * HEADS_ + h) * (size_t)DH_ * N_;
#pragma unroll
        for (int mb = 0; mb < 4; ++mb)
#pragma unroll
            for (int r = 0; r < 4; ++r)
                dst[(size_t)(mb*16 + quad*4 + r) * N_ + n] = f2bf(acc[mb][r]);
    }
}

// ---------------- Kernel 2: flash attention (S^T/O^T, fixed-max, scalar-reg prefetch) --
// Prefetch regs are FOUR NAMED uint4 scalars (not arrays) loaded UNCONDITIONALLY
// with a clamped tile index — guarantees VGPR allocation (R10's array+branch
// version was demoted to scratch: 521 MB of HBM writes).
__global__ __launch_bounds__(256) void k_attn(const u16* __restrict__ Qn,
                                              const u16* __restrict__ Kn,
                                              const u16* __restrict__ Vt,
                                              u16* __restrict__ AO) {
    __shared__ __align__(16) u16 Kt[64][72];        // k-rows x d (pad 8)
    __shared__ __align__(16) u16 Vtl[64][72];       // d-rows x k (pad 8)
    __shared__ __align__(16) u16 plds[4][16][72];   // per-wave P^T [q][k]
    int head_lin = blockIdx.x & 31;                 // head -> XCD pinning
    int qt = blockIdx.x >> 5;
    int b = head_lin >> 3, h = head_lin & 7;
    int tid = threadIdx.x;
    int wv = tid >> 6, lane = tid & 63;
    int col = lane & 15, quad = lane >> 4;
    size_t head = (size_t)b * HEADS_ + h;
    const u16* Qh = Qn + head * (size_t)N_ * DH_;
    const u16* Kh = Kn + head * (size_t)N_ * DH_;
    const u16* Vh = Vt + head * (size_t)DH_ * N_;
    int q0 = qt * 64 + wv * 16;
    bf16x8 qf0 = *(const bf16x8*)(Qh + (size_t)(q0 + col) * DH_ + quad*8);
    bf16x8 qf1 = *(const bf16x8*)(Qh + (size_t)(q0 + col) * DH_ + 32 + quad*8);
    f32x4 z = {0.f, 0.f, 0.f, 0.f};
    f32x4 O[4]; O[0]=z; O[1]=z; O[2]=z; O[3]=z;
    float l_i = 0.f;
    int vrow0 = tid >> 3, vseg = tid & 7;
    int krow0 = tid >> 3, kseg = tid & 7;           // commit coords (p=0)
    const u16* ksrc0 = Kh + (size_t)tid * 8;
    const u16* vsrc0 = Vh + (size_t)vrow0 * N_ + vseg * 8;

    uint4 kreg0 = *(const uint4*)(ksrc0);
    uint4 kreg1 = *(const uint4*)(ksrc0 + 2048);
    uint4 vreg0 = *(const uint4*)(vsrc0);
    uint4 vreg1 = *(const uint4*)(vsrc0 + (size_t)32 * N_);

    for (int kt = 0; kt < N_/64; ++kt) {            // 36 iterations
        // commit prefetched tile to LDS
        *(uint4*)(&Kt[krow0][kseg*8])      = kreg0;
        *(uint4*)(&Kt[32 + krow0][kseg*8]) = kreg1;
        *(uint4*)(&Vtl[vrow0][vseg*8])      = vreg0;
        *(uint4*)(&Vtl[32 + vrow0][vseg*8]) = vreg1;
        __syncthreads();   // tile visible
        // unconditional clamped prefetch of tile kt+1 (hidden behind compute)
        int ktn = kt + 1 < N_/64 ? kt + 1 : kt;
        kreg0 = *(const uint4*)(ksrc0 + (size_t)ktn * 4096);
        kreg1 = *(const uint4*)(ksrc0 + (size_t)ktn * 4096 + 2048);
        vreg0 = *(const uint4*)(vsrc0 + ktn * 64);
        vreg1 = *(const uint4*)(vsrc0 + (size_t)32 * N_ + ktn * 64);
        // S^T + fixed-max softmax + pack
        float rs = 0.f;
#pragma unroll
        for (int nb = 0; nb < 4; ++nb) {
            f32x4 a = z;
            a = MFMA16(*(const bf16x8*)(&Kt[nb*16 + col][quad*8]), qf0, a);
            a = MFMA16(*(const bf16x8*)(&Kt[nb*16 + col][32 + quad*8]), qf1, a);
            float p0 = exp2f(fmaf(a[0], SCALE_LOG2E, -SCALE_LOG2E));
            float p1 = exp2f(fmaf(a[1], SCALE_LOG2E, -SCALE_LOG2E));
            float p2 = exp2f(fmaf(a[2], SCALE_LOG2E, -SCALE_LOG2E));
            float p3 = exp2f(fmaf(a[3], SCALE_LOG2E, -SCALE_LOG2E));
            rs += (p0 + p1) + (p2 + p3);
            uint2 w;
            w.x = pk2(p0, p1);
            w.y = pk2(p2, p3);
            *(uint2*)(&plds[wv][col][nb*16 + quad*4]) = w;
        }
        l_i += rs;
        __asm__ volatile("" ::: "memory");   // wave-private plds ordering
        // O^T += V^T P^T
#pragma unroll
        for (int ks = 0; ks < 2; ++ks) {
            bf16x8 pf = *(const bf16x8*)(&plds[wv][col][ks*32 + quad*8]);
#pragma unroll
            for (int nb = 0; nb < 4; ++nb) {
                bf16x8 vf = *(const bf16x8*)(&Vtl[nb*16 + col][ks*32 + quad*8]);
                O[nb] = MFMA16(vf, pf, O[nb]);
            }
        }
        __asm__ volatile("" ::: "memory");   // WAR vs next iter's plds writes
        __syncthreads();   // all tile reads done before next iter's commits
    }
    l_i += __shfl_xor(l_i, 16);
    l_i += __shfl_xor(l_i, 32);
    float linv = 1.f / l_i;
    u16* dst = AO + ((size_t)b * N_ + q0 + col) * INNER_ + h * DH_;
#pragma unroll
    for (int nb = 0; nb < 4; ++nb) {
        uint2 w;
        w.x = pk2(O[nb][0] * linv, O[nb][1] * linv);
        w.y = pk2(O[nb][2] * linv, O[nb][3] * linv);
        *(uint2*)(dst + nb*16 + quad*4) = w;
    }
}

// ---------------- Kernel 3: output projection (LDS-staged) + bias ----------------
__global__ __launch_bounds__(256) void k_proj(const u16* __restrict__ w_out,
                                              const float* __restrict__ b_out,
                                              const u16* __restrict__ AO,
                                              float* __restrict__ out) {
    __shared__ __align__(16) u16 Wt[64][264];
    __shared__ __align__(16) u16 At[64][264];
    int mt = blockIdx.x, nt = blockIdx.y, b = blockIdx.z;
    int tid = threadIdx.x;
    int wv = tid >> 6, lane = tid & 63;
    int col = lane & 15, quad = lane >> 4;
    int o0b = mt * 64;
    const u16* wtile = w_out + (size_t)o0b * INNER_;
    const u16* atile = AO + ((size_t)b * N_ + nt*64) * INNER_;
    f32x4 z = {0.f, 0.f, 0.f, 0.f};
    f32x4 acc[4]; acc[0]=z; acc[1]=z; acc[2]=z; acc[3]=z;
#pragma unroll
    for (int half = 0; half < 2; ++half) {
        if (half) __syncthreads();
#pragma unroll
        for (int p = 0; p < 8; ++p) {
            int c = p * 256 + tid;
            int row = c >> 5, seg = c & 31;
            *(uint4*)(&Wt[row][seg*8]) =
                *(const uint4*)(wtile + (size_t)row * INNER_ + half*256 + seg*8);
            *(uint4*)(&At[row][seg*8]) =
                *(const uint4*)(atile + (size_t)row * INNER_ + half*256 + seg*8);
        }
        __syncthreads();
#pragma unroll
        for (int ks = 0; ks < 8; ++ks) {
            bf16x8 af = *(const bf16x8*)(&Wt[wv*16 + col][ks*32 + quad*8]);
#pragma unroll
            for (int nb = 0; nb < 4; ++nb) {
                bf16x8 bfv = *(const bf16x8*)(&At[nb*16 + col][ks*32 + quad*8]);
                acc[nb] = MFMA16(af, bfv, acc[nb]);
            }
        }
    }
    int o0 = o0b + wv * 16;
    float bias[4];
#pragma unroll
    for (int r = 0; r < 4; ++r) bias[r] = b_out[o0 + quad*4 + r];
    float* dst = out + ((size_t)b * C_ + o0) * N_ + nt*64;
#pragma unroll
    for (int nb = 0; nb < 4; ++nb)
#pragma unroll
        for (int r = 0; r < 4; ++r)
            dst[(size_t)(quad*4 + r) * N_ + nb*16 + col] = acc[nb][r] + bias[r];
}

// ---------------- launch ----------------
extern "C" void kernel_launch(void* const* d_in, const int* in_sizes, int n_in,
                              void* d_out, int out_size, void* d_ws, size_t ws_size,
                              hipStream_t stream) {
    const float* x     = (const float*)d_in[0];
    const float* w_qkv = (const float*)d_in[1];
    const float* w_out = (const float*)d_in[2];
    const float* b_out = (const float*)d_in[3];
    float* out = (float*)d_out;

    char* ws = (char*)d_ws;
    u16* xT  = (u16*)(ws);
    u16* Qn  = (u16*)(ws + 4718592);
    u16* Kn  = (u16*)(ws + 14155776);
    u16* Vt  = (u16*)(ws + 23592960);
    u16* AO  = (u16*)(ws + 33030144);
    u16* wqb = (u16*)(ws + 42467328);
    u16* wob = (u16*)(ws + 43253760);

    hipLaunchKernelGGL(k_prep, dim3(1088), dim3(256), 0, stream, x, xT, w_qkv, wqb, w_out, wob);
    hipLaunchKernelGGL(k_qkv,  dim3(24, N_/64, B_), dim3(256), 0, stream, wqb, xT, Qn, Kn, Vt);
    hipLaunchKernelGGL(k_attn, dim3((N_/64) * 32), dim3(256), 0, stream, Qn, Kn, Vt, AO);
    hipLaunchKernelGGL(k_proj, dim3(C_/64, N_/64, B_), dim3(256), 0, stream, wob, b_out, AO, out);
}